// Round 4
// baseline (562.645 us; speedup 1.0000x reference)
//
#include <hip/hip_runtime.h>
#include <hip/hip_bf16.h>
#include <math.h>

// Problem constants (fixed by reference): B=2,T=2048 -> N=4096 tokens
#define N_TOK 4096
#define D_DIM 1024
#define H_DIM 4096
#define E_NUM 8
#define NSLOT (N_TOK * 2)  // total assignments = N*TOPK = 8192

typedef short bf16x8 __attribute__((ext_vector_type(8)));
typedef float f32x4 __attribute__((ext_vector_type(4)));

// ---------------- helpers ----------------

__device__ __forceinline__ unsigned short f2bf(float f) {
  unsigned int u = __float_as_uint(f);
  u += 0x7FFFu + ((u >> 16) & 1u);  // round-to-nearest-even
  return (unsigned short)(u >> 16);
}

// async global->LDS, 16B per lane (dest = wave-uniform base + lane*16, m104)
__device__ __forceinline__ void gld_lds16(const void* g, void* l) {
  __builtin_amdgcn_global_load_lds(
      (__attribute__((address_space(1))) void*)(g),
      (__attribute__((address_space(3))) void*)(l), 16, 0, 0);
}

// ---------------- fused weight conversion (wfc + wproj in one dispatch) ----

__global__ void cvt_w(const float* __restrict__ wfc, const float* __restrict__ wproj,
                      unsigned short* __restrict__ wfcb, unsigned short* __restrict__ wpjb) {
  int i = blockIdx.x * 256 + threadIdx.x;  // 0..16777215 float4 groups
  float4 v;
  ushort4 o;
  if (i < 8388608) {
    v = ((const float4*)wfc)[i];
    o.x = f2bf(v.x); o.y = f2bf(v.y); o.z = f2bf(v.z); o.w = f2bf(v.w);
    ((ushort4*)wfcb)[i] = o;
  } else {
    int k = i - 8388608;
    v = ((const float4*)wproj)[k];
    o.x = f2bf(v.x); o.y = f2bf(v.y); o.z = f2bf(v.z); o.w = f2bf(v.w);
    ((ushort4*)wpjb)[k] = o;
  }
}

// ---------------- gating (atomic-free) + fused x->bf16 conversion ----------

__global__ void gating_kernel(const float* __restrict__ x,
                              const float* __restrict__ wg,
                              float* __restrict__ probs,   // [N_TOK][E]
                              int* __restrict__ eidx,
                              float* __restrict__ rw,
                              unsigned short* __restrict__ xb) {
  __shared__ float4 wg_lds[2048];  // 8*1024 floats = 32 KB
  const int t = threadIdx.x;
  const int lane = t & 63;
  const int wave = t >> 6;

#pragma unroll
  for (int j = 0; j < 8; ++j)
    wg_lds[t + 256 * j] = ((const float4*)wg)[t + 256 * j];
  __syncthreads();

#pragma unroll
  for (int j = 0; j < 4; ++j) {
    const int n = blockIdx.x * 16 + wave * 4 + j;
    const float4* xr = (const float4*)(x + (size_t)n * D_DIM);
    ushort4* xw = (ushort4*)(xb + (size_t)n * D_DIM);

    float acc[E_NUM];
#pragma unroll
    for (int e = 0; e < E_NUM; ++e) acc[e] = 0.f;

#pragma unroll
    for (int i = 0; i < 4; ++i) {
      float4 xv = xr[lane + 64 * i];
      ushort4 xo;
      xo.x = f2bf(xv.x); xo.y = f2bf(xv.y); xo.z = f2bf(xv.z); xo.w = f2bf(xv.w);
      xw[lane + 64 * i] = xo;  // fused x conversion (row read once anyway)
#pragma unroll
      for (int e = 0; e < E_NUM; ++e) {
        float4 wv = wg_lds[e * 256 + lane + 64 * i];
        acc[e] += xv.x * wv.x + xv.y * wv.y + xv.z * wv.z + xv.w * wv.w;
      }
    }
#pragma unroll
    for (int m = 1; m < 64; m <<= 1) {
#pragma unroll
      for (int e = 0; e < E_NUM; ++e) acc[e] += __shfl_xor(acc[e], m, 64);
    }

    float mx = acc[0];
#pragma unroll
    for (int e = 1; e < E_NUM; ++e) mx = fmaxf(mx, acc[e]);
    float p[E_NUM], s = 0.f;
#pragma unroll
    for (int e = 0; e < E_NUM; ++e) { p[e] = __expf(acc[e] - mx); s += p[e]; }
    float inv = 1.f / s;

    if (lane < E_NUM) probs[(size_t)n * E_NUM + lane] = p[lane] * inv;

    if (lane == 0) {
      int i1 = 0;
#pragma unroll
      for (int e = 1; e < E_NUM; ++e) if (p[e] > p[i1]) i1 = e;
      int i2 = (i1 == 0) ? 1 : 0;
#pragma unroll
      for (int e = 0; e < E_NUM; ++e)
        if (e != i1 && p[e] > p[i2]) i2 = e;
      float p1 = p[i1], p2 = p[i2];
      float wsum = 1.f / (p1 + p2);  // top-2 renormalize (softmax scale cancels)
      eidx[n] = i1 | (i2 << 8);
      rw[2 * n] = p1 * wsum;
      rw[2 * n + 1] = p2 * wsum;
    }
  }
}

// ---------------- fused route: sums + histogram + scan + scatter + loss ----
// Single block. Deterministic scatter via per-thread exclusive prefix (no
// atomics at all): thread t reserves [base[e], base[e]+cnt_t[e]) per expert.

__global__ void reduce_route(const float* __restrict__ probs,
                             const int* __restrict__ eidx,
                             int* __restrict__ counts,
                             int* __restrict__ offsets,
                             int* __restrict__ tok_id,
                             int* __restrict__ inv,
                             const float* __restrict__ rw_unused,
                             float* __restrict__ loss) {
  const int t = threadIdx.x;
  // --- prob partial sums (coalesced float4; parity(t) fixes expert group) ---
  float4 part = make_float4(0.f, 0.f, 0.f, 0.f);
  for (int j = 0; j < 32; ++j) {
    float4 v = ((const float4*)probs)[t + 256 * j];
    part.x += v.x; part.y += v.y; part.z += v.z; part.w += v.w;
  }
  // --- per-thread histogram over its 16 tokens (n = t + 256j) ---
  int cnt[E_NUM];
#pragma unroll
  for (int e = 0; e < E_NUM; ++e) cnt[e] = 0;
  int pkc[16];
  for (int j = 0; j < 16; ++j) {
    int pk = eidx[t + 256 * j];
    pkc[j] = pk;
    int e1 = pk & 255, e2 = pk >> 8;
#pragma unroll
    for (int e = 0; e < E_NUM; ++e) cnt[e] += (e1 == e) + (e2 == e);
  }

  // --- inclusive scan over 256 threads x 8 experts (stride 9 pads banks) ---
  __shared__ int sc[256 * 9];
#pragma unroll
  for (int e = 0; e < E_NUM; ++e) sc[t * 9 + e] = cnt[e];
  __syncthreads();
  for (int s = 1; s < 256; s <<= 1) {
    int v[E_NUM];
#pragma unroll
    for (int e = 0; e < E_NUM; ++e) v[e] = (t >= s) ? sc[(t - s) * 9 + e] : 0;
    __syncthreads();
#pragma unroll
    for (int e = 0; e < E_NUM; ++e) sc[t * 9 + e] += v[e];
    __syncthreads();
  }

  // --- prob column totals (tree) ---
  __shared__ float redf[256 * E_NUM];
  const int eb = (t & 1) * 4;
#pragma unroll
  for (int e = 0; e < E_NUM; ++e) redf[t * E_NUM + e] = 0.f;
  redf[t * E_NUM + eb + 0] = part.x;
  redf[t * E_NUM + eb + 1] = part.y;
  redf[t * E_NUM + eb + 2] = part.z;
  redf[t * E_NUM + eb + 3] = part.w;
  __syncthreads();
  for (int s = 128; s > 0; s >>= 1) {
    if (t < s) {
#pragma unroll
      for (int e = 0; e < E_NUM; ++e)
        redf[t * E_NUM + e] += redf[(t + s) * E_NUM + e];
    }
    __syncthreads();
  }

  __shared__ int offs_s[E_NUM];
  if (t == 0) {
    int o = 0;
    float L = 0.f;
    for (int e = 0; e < E_NUM; ++e) {
      int c = sc[255 * 9 + e];
      counts[e] = c;
      offsets[e] = o;
      offs_s[e] = o;
      o += c;
      L += redf[e] * (float)c;
    }
    loss[0] = L * (float)E_NUM / ((float)N_TOK * (float)N_TOK);
  }
  __syncthreads();

  // --- deterministic scatter from reserved ranges ---
  int base[E_NUM];
#pragma unroll
  for (int e = 0; e < E_NUM; ++e) base[e] = offs_s[e] + sc[t * 9 + e] - cnt[e];
  for (int j = 0; j < 16; ++j) {
    int n = t + 256 * j;
    int pk = pkc[j];
    int e1 = pk & 255, e2 = pk >> 8;
    int pos1 = 0, pos2 = 0;
#pragma unroll
    for (int e = 0; e < E_NUM; ++e) {
      if (e1 == e) pos1 = base[e]++;
    }
#pragma unroll
    for (int e = 0; e < E_NUM; ++e) {
      if (e2 == e) pos2 = base[e]++;
    }
    tok_id[pos1] = n; inv[2 * n] = pos1;
    tok_id[pos2] = n; inv[2 * n + 1] = pos2;
  }
}

// ---------------- grouped GEMMs ----------------
// 128x128x64 tile, 4 waves. C[m][n] = sum_k A[m][k]*B[n][k].
// XOR source swizzle (R3, measured 0 conflicts): LDS[row][chunk c] holds
// global chunk c ^ (row&7).
// R4: B-fragment remap — bfr[j] holds B row wn + 4*(lane&15) + j, so lane ln
// owns OUTPUT COLS wn+4ln..wn+4ln+3 (contiguous) -> vectorized epilogues.
// Read pattern stays uniform over the 8 chunk-columns -> conflict-free.

__launch_bounds__(256, 2)
__global__ void gemm_fc(const unsigned short* __restrict__ xb,    // [N_TOK][D]
                        const unsigned short* __restrict__ wfc,   // [E][H][D] bf16
                        const int* __restrict__ tok_id,
                        const int* __restrict__ counts,
                        const int* __restrict__ offsets,
                        unsigned short* __restrict__ hbuf) {      // [NSLOT][H]
  const int e = blockIdx.z;
  const int cnt = counts[e];
  const int mtile = blockIdx.y;
  if (mtile * 128 >= cnt) return;
  const int ntile = blockIdx.x;
  const int off = offsets[e];

  __shared__ __align__(16) unsigned short As[128 * 64];
  __shared__ __align__(16) unsigned short Bs[128 * 64];

  const int t = threadIdx.x;
  const int lane = t & 63;
  const int wave = t >> 6;
  const int wm = (wave >> 1) * 64;
  const int wn = (wave & 1) * 64;
  const int srow = t >> 3;
  const int seg = (t & 7) ^ (srow & 7);  // XOR-swizzled source chunk

  const unsigned short* aptr[4];
  const unsigned short* bptr[4];
#pragma unroll
  for (int p = 0; p < 4; ++p) {
    int r = mtile * 128 + p * 32 + srow;
    r = (r < cnt) ? r : (cnt - 1);  // clamp: masked at store
    int tok = tok_id[off + r];
    aptr[p] = xb + (size_t)tok * D_DIM + seg * 8;
    int br = ntile * 128 + p * 32 + srow;
    bptr[p] = wfc + ((size_t)e * H_DIM + br) * D_DIM + seg * 8;
  }

  f32x4 acc[4][4];
#pragma unroll
  for (int i = 0; i < 4; ++i)
#pragma unroll
    for (int j = 0; j < 4; ++j) acc[i][j] = (f32x4){0.f, 0.f, 0.f, 0.f};

  const int ln = lane & 15;
  const int q = lane >> 4;

  for (int k0 = 0; k0 < D_DIM; k0 += 64) {
#pragma unroll
    for (int p = 0; p < 4; ++p) {
      gld_lds16(aptr[p] + k0, &As[p * 2048 + t * 8]);
      gld_lds16(bptr[p] + k0, &Bs[p * 2048 + t * 8]);
    }
    __syncthreads();
#pragma unroll
    for (int kk = 0; kk < 64; kk += 32) {
      const int g = (kk >> 3) + q;
      bf16x8 af[4], bfr[4];
#pragma unroll
      for (int i = 0; i < 4; ++i)
        af[i] = *(const bf16x8*)&As[(wm + ln + i * 16) * 64 + ((g ^ (ln & 7)) << 3)];
#pragma unroll
      for (int j = 0; j < 4; ++j) {
        int rb = wn + 4 * ln + j;
        bfr[j] = *(const bf16x8*)&Bs[rb * 64 + ((g ^ (rb & 7)) << 3)];
      }
#pragma unroll
      for (int i = 0; i < 4; ++i)
#pragma unroll
        for (int j = 0; j < 4; ++j)
          acc[i][j] = __builtin_amdgcn_mfma_f32_16x16x32_bf16(af[i], bfr[j], acc[i][j], 0, 0, 0);
    }
    __syncthreads();
  }

  // epilogue: h = relu(t)^2, cast bf16, ushort4 store (lane owns 4 contig cols)
#pragma unroll
  for (int i = 0; i < 4; ++i) {
#pragma unroll
    for (int r = 0; r < 4; ++r) {
      int m = mtile * 128 + wm + i * 16 + q * 4 + r;
      if (m < cnt) {
        float v0 = acc[i][0][r], v1 = acc[i][1][r], v2 = acc[i][2][r], v3 = acc[i][3][r];
        v0 = v0 > 0.f ? v0 * v0 : 0.f;
        v1 = v1 > 0.f ? v1 * v1 : 0.f;
        v2 = v2 > 0.f ? v2 * v2 : 0.f;
        v3 = v3 > 0.f ? v3 * v3 : 0.f;
        ushort4 o;
        o.x = f2bf(v0); o.y = f2bf(v1); o.z = f2bf(v2); o.w = f2bf(v3);
        *(ushort4*)&hbuf[(size_t)(off + m) * H_DIM + ntile * 128 + wn + 4 * ln] = o;
      }
    }
  }
}

// split-K=2, atomic-free: each (kq,slot) row of fp32 partials stored with
// plain float4 writes; combine kernel sums. partial aliases wfcb (proj runs
// after gemm_fc has consumed the weights; sizes match exactly, 64 MiB).
__launch_bounds__(256, 2)
__global__ void gemm_proj(const unsigned short* __restrict__ hbuf,   // [NSLOT][H]
                          const unsigned short* __restrict__ wproj,  // [E][D][H] bf16
                          const int* __restrict__ counts,
                          const int* __restrict__ offsets,
                          float* __restrict__ partial) {             // [2][NSLOT][D]
  const int e = blockIdx.z >> 1;
  const int kq = blockIdx.z & 1;
  const int kbase = kq * (H_DIM / 2);
  const int cnt = counts[e];
  const int mtile = blockIdx.y;
  if (mtile * 128 >= cnt) return;
  const int ntile = blockIdx.x;  // 0..7 (D=1024)
  const int off = offsets[e];

  __shared__ __align__(16) unsigned short As[128 * 64];
  __shared__ __align__(16) unsigned short Bs[128 * 64];

  const int t = threadIdx.x;
  const int lane = t & 63;
  const int wave = t >> 6;
  const int wm = (wave >> 1) * 64;
  const int wn = (wave & 1) * 64;
  const int srow = t >> 3;
  const int seg = (t & 7) ^ (srow & 7);

  const unsigned short* aptr[4];
  const unsigned short* bptr[4];
#pragma unroll
  for (int p = 0; p < 4; ++p) {
    int r = mtile * 128 + p * 32 + srow;
    r = (r < cnt) ? r : (cnt - 1);
    aptr[p] = hbuf + (size_t)(off + r) * H_DIM + seg * 8;
    int br = ntile * 128 + p * 32 + srow;
    bptr[p] = wproj + ((size_t)e * D_DIM + br) * H_DIM + seg * 8;
  }

  f32x4 acc[4][4];
#pragma unroll
  for (int i = 0; i < 4; ++i)
#pragma unroll
    for (int j = 0; j < 4; ++j) acc[i][j] = (f32x4){0.f, 0.f, 0.f, 0.f};

  const int ln = lane & 15;
  const int q = lane >> 4;

  for (int k0 = kbase; k0 < kbase + H_DIM / 2; k0 += 64) {
#pragma unroll
    for (int p = 0; p < 4; ++p) {
      gld_lds16(aptr[p] + k0, &As[p * 2048 + t * 8]);
      gld_lds16(bptr[p] + k0, &Bs[p * 2048 + t * 8]);
    }
    __syncthreads();
#pragma unroll
    for (int kk = 0; kk < 64; kk += 32) {
      const int g = (kk >> 3) + q;
      bf16x8 af[4], bfr[4];
#pragma unroll
      for (int i = 0; i < 4; ++i)
        af[i] = *(const bf16x8*)&As[(wm + ln + i * 16) * 64 + ((g ^ (ln & 7)) << 3)];
#pragma unroll
      for (int j = 0; j < 4; ++j) {
        int rb = wn + 4 * ln + j;
        bfr[j] = *(const bf16x8*)&Bs[rb * 64 + ((g ^ (rb & 7)) << 3)];
      }
#pragma unroll
      for (int i = 0; i < 4; ++i)
#pragma unroll
        for (int j = 0; j < 4; ++j)
          acc[i][j] = __builtin_amdgcn_mfma_f32_16x16x32_bf16(af[i], bfr[j], acc[i][j], 0, 0, 0);
    }
    __syncthreads();
  }

  // epilogue: plain float4 store of this K-half's partial (no atomics)
#pragma unroll
  for (int i = 0; i < 4; ++i) {
#pragma unroll
    for (int r = 0; r < 4; ++r) {
      int m = mtile * 128 + wm + i * 16 + q * 4 + r;
      if (m < cnt) {
        float4 o = make_float4(acc[i][0][r], acc[i][1][r], acc[i][2][r], acc[i][3][r]);
        *(float4*)&partial[((size_t)(kq * NSLOT + off + m)) * D_DIM + ntile * 128 + wn + 4 * ln] = o;
      }
    }
  }
}

// combine: out[n] = rw[2n]*(P0+P1)[inv[2n]] + rw[2n+1]*(P0+P1)[inv[2n+1]]
__global__ void combine(const float* __restrict__ partial,
                        const int* __restrict__ inv,
                        const float* __restrict__ rw,
                        float* __restrict__ out) {
  const int n = blockIdx.x;
  const int t = threadIdx.x;  // 256 threads x float4 = 1024 cols
  const int d1 = inv[2 * n], d2 = inv[2 * n + 1];
  const float w1 = rw[2 * n], w2 = rw[2 * n + 1];
  const float4* p0 = (const float4*)partial;
  const float4* p1 = (const float4*)(partial + (size_t)NSLOT * D_DIM);
  float4 a = p0[(size_t)d1 * 256 + t];
  float4 b = p1[(size_t)d1 * 256 + t];
  float4 c = p0[(size_t)d2 * 256 + t];
  float4 d = p1[(size_t)d2 * 256 + t];
  float4 o;
  o.x = w1 * (a.x + b.x) + w2 * (c.x + d.x);
  o.y = w1 * (a.y + b.y) + w2 * (c.y + d.y);
  o.z = w1 * (a.z + b.z) + w2 * (c.z + d.z);
  o.w = w1 * (a.w + b.w) + w2 * (c.w + d.w);
  ((float4*)out)[(size_t)n * 256 + t] = o;
}

// ---------------- launch ----------------
// ws layout (bytes):
//   0        counts[8] | 64 offsets[8]
//   256      eidx[4096] (16384) | 16640 rw[8192] (32768)
//   49408    tok_id[8192] (32768) | 82176 inv[8192] (32768)
//   114944   probs[4096*8]         (131072)
//   246016   x_bf16                (8388608)
//   8634624  wfc_bf16              (67108864)  <- aliased as partial[2][8192][1024] fp32 in proj phase
//   75743488 wproj_bf16            (67108864)
//   142852352 hbuf                 (67108864)
//   total: 209961216 (~200 MiB)

extern "C" void kernel_launch(void* const* d_in, const int* in_sizes, int n_in,
                              void* d_out, int out_size, void* d_ws, size_t ws_size,
                              hipStream_t stream) {
  (void)in_sizes; (void)n_in; (void)out_size; (void)ws_size;
  const float* x = (const float*)d_in[0];
  const float* wg = (const float*)d_in[1];
  const float* wfc = (const float*)d_in[2];
  const float* wproj = (const float*)d_in[3];
  float* out = (float*)d_out;
  char* ws = (char*)d_ws;

  int* counts = (int*)(ws + 0);
  int* offsets = (int*)(ws + 64);
  int* eidx = (int*)(ws + 256);
  float* rw = (float*)(ws + 16640);
  int* tok_id = (int*)(ws + 49408);
  int* inv = (int*)(ws + 82176);
  float* probs = (float*)(ws + 114944);
  unsigned short* xb = (unsigned short*)(ws + 246016);
  unsigned short* wfcb = (unsigned short*)(ws + 8634624);
  float* partial = (float*)(ws + 8634624);  // alias: safe after gemm_fc
  unsigned short* wpjb = (unsigned short*)(ws + 75743488);
  unsigned short* hbuf = (unsigned short*)(ws + 142852352);

  hipLaunchKernelGGL(cvt_w, dim3(65536), dim3(256), 0, stream, wfc, wproj, wfcb, wpjb);
  hipLaunchKernelGGL(gating_kernel, dim3(256), dim3(256), 0, stream, x, wg, probs, eidx, rw, xb);
  hipLaunchKernelGGL(reduce_route, dim3(1), dim3(256), 0, stream, probs, eidx, counts, offsets,
                     tok_id, inv, rw, out + 4194304);
  hipLaunchKernelGGL(gemm_fc, dim3(32, 32, 8), dim3(256), 0, stream, xb, wfcb, tok_id, counts, offsets, hbuf);
  hipLaunchKernelGGL(gemm_proj, dim3(8, 32, 16), dim3(256), 0, stream, hbuf, wpjb, counts, offsets, partial);
  hipLaunchKernelGGL(combine, dim3(4096), dim3(256), 0, stream, partial, inv, rw, out);
}